// Round 1
// baseline (233.313 us; speedup 1.0000x reference)
//
#include <hip/hip_runtime.h>

typedef __attribute__((ext_vector_type(8))) short bf16x8;
typedef __attribute__((ext_vector_type(4))) float f32x4;

#define DI __device__ __forceinline__

DI unsigned short f2bf(float f) {
    unsigned int u = __builtin_bit_cast(unsigned int, f);
    u += 0x7fff + ((u >> 16) & 1);
    return (unsigned short)(u >> 16);
}

// ---------------------------------------------------------------------------
// Kernel 1: projections  q = (x@Wq)*0.125, k = x@Wk, v = x@Wv   (bf16 out)
// M=16384 rows (B*T), N=64, K=1024.  64 rows per block, 4 waves.
// ---------------------------------------------------------------------------
__global__ __launch_bounds__(256) void proj_kernel(
    const float* __restrict__ x,
    const float* __restrict__ Wq,
    const float* __restrict__ Wk,
    const float* __restrict__ Wv,
    unsigned short* __restrict__ qw,
    unsigned short* __restrict__ kw,
    unsigned short* __restrict__ vw)
{
    __shared__ unsigned short xs[64][64];       // [row][k]  8KB
    __shared__ unsigned short ws3[3][64][64];   // [mat][col][k] 24KB (transposed)

    const int tid = threadIdx.x;
    const int w = tid >> 6, l = tid & 63;
    const int row0 = blockIdx.x * 64;
    const int lr = tid >> 2;            // staging row 0..63
    const int c0 = (tid & 3) * 16;      // staging col 0,16,32,48

    f32x4 acc[3][4];
    #pragma unroll
    for (int m = 0; m < 3; ++m)
        #pragma unroll
        for (int t = 0; t < 4; ++t) {
            f32x4 z = {0.f, 0.f, 0.f, 0.f};
            acc[m][t] = z;
        }

    const float* Wm[3] = {Wq, Wk, Wv};

    for (int ks = 0; ks < 16; ++ks) {
        __syncthreads();
        // stage x tile (64x64) as bf16, row-major
        {
            const float* src = x + (size_t)(row0 + lr) * 1024 + ks * 64 + c0;
            #pragma unroll
            for (int j = 0; j < 4; ++j) {
                float4 v = *(const float4*)(src + 4 * j);
                xs[lr][c0 + 4*j + 0] = f2bf(v.x);
                xs[lr][c0 + 4*j + 1] = f2bf(v.y);
                xs[lr][c0 + 4*j + 2] = f2bf(v.z);
                xs[lr][c0 + 4*j + 3] = f2bf(v.w);
            }
        }
        // stage Wq/Wk/Wv tiles (64x64), transposed -> [col][k]
        #pragma unroll
        for (int m = 0; m < 3; ++m) {
            const float* src = Wm[m] + (size_t)(ks * 64 + lr) * 64 + c0;
            #pragma unroll
            for (int j = 0; j < 4; ++j) {
                float4 v = *(const float4*)(src + 4 * j);
                ws3[m][c0 + 4*j + 0][lr] = f2bf(v.x);
                ws3[m][c0 + 4*j + 1][lr] = f2bf(v.y);
                ws3[m][c0 + 4*j + 2][lr] = f2bf(v.z);
                ws3[m][c0 + 4*j + 3][lr] = f2bf(v.w);
            }
        }
        __syncthreads();

        // A fragments (16 rows per wave)
        bf16x8 a[2];
        #pragma unroll
        for (int h = 0; h < 2; ++h)
            a[h] = *(const bf16x8*)&xs[w * 16 + (l & 15)][8 * (l >> 4) + 32 * h];

        #pragma unroll
        for (int m = 0; m < 3; ++m)
            #pragma unroll
            for (int t = 0; t < 4; ++t)
                #pragma unroll
                for (int h = 0; h < 2; ++h) {
                    bf16x8 b = *(const bf16x8*)&ws3[m][(l & 15) + 16 * t][8 * (l >> 4) + 32 * h];
                    acc[m][t] = __builtin_amdgcn_mfma_f32_16x16x32_bf16(a[h], b, acc[m][t], 0, 0, 0);
                }
    }

    // epilogue: D layout col = l&15 (+16t), row = (l>>4)*4 + i
    unsigned short* dst[3] = {qw, kw, vw};
    #pragma unroll
    for (int m = 0; m < 3; ++m) {
        const float sc = (m == 0) ? 0.125f : 1.0f;
        #pragma unroll
        for (int t = 0; t < 4; ++t)
            #pragma unroll
            for (int i = 0; i < 4; ++i) {
                int row = row0 + w * 16 + (l >> 4) * 4 + i;
                int col = (l & 15) + 16 * t;
                dst[m][(size_t)row * 64 + col] = f2bf(acc[m][t][i] * sc);
            }
    }
}

// ---------------------------------------------------------------------------
// Kernel 2: flash attention.  One WG (4 waves) per (batch, 64-row q-block).
// Each wave owns 16 q rows.  Key tiles of 64 staged in LDS.
// ---------------------------------------------------------------------------
__global__ __launch_bounds__(256) void attn_kernel(
    const unsigned short* __restrict__ qw,
    const unsigned short* __restrict__ kw,
    const unsigned short* __restrict__ vw,
    float* __restrict__ out)
{
    __shared__ unsigned short Ks[64][64];      // [key][d]   8KB
    __shared__ unsigned short Vs[64][64];      // [d][key]   8KB (transposed)
    __shared__ unsigned short Ps[4][16][64];   // per-wave P [row][key] 8KB

    const int tid = threadIdx.x;
    const int w = tid >> 6, l = tid & 63;
    const int b = blockIdx.y;
    const int bq = blockIdx.x * 64;
    const size_t base = (size_t)b * 4096;

    // Q fragments for this wave's 16 rows (scale already folded in)
    bf16x8 aq[2];
    {
        int row = bq + w * 16 + (l & 15);
        #pragma unroll
        for (int h = 0; h < 2; ++h)
            aq[h] = *(const bf16x8*)(qw + (base + row) * 64 + 8 * (l >> 4) + 32 * h);
    }

    f32x4 accO[4];
    #pragma unroll
    for (int t = 0; t < 4; ++t) { f32x4 z = {0.f,0.f,0.f,0.f}; accO[t] = z; }
    f32x4 mrow = {-1e30f, -1e30f, -1e30f, -1e30f};
    f32x4 lsum = {0.f, 0.f, 0.f, 0.f};

    const int nt = bq / 64 + 1;
    const int lr = tid >> 2;
    const int d0 = (tid & 3) * 16;

    for (int it = 0; it < nt; ++it) {
        const int k0 = it * 64;
        __syncthreads();
        // stage K (row-major) and V (transposed)
        {
            const unsigned short* srcK = kw + (base + k0 + lr) * 64 + d0;
            *(bf16x8*)&Ks[lr][d0]     = *(const bf16x8*)(srcK);
            *(bf16x8*)&Ks[lr][d0 + 8] = *(const bf16x8*)(srcK + 8);
            const unsigned short* srcV = vw + (base + k0 + lr) * 64 + d0;
            #pragma unroll
            for (int j = 0; j < 16; ++j)
                Vs[d0 + j][lr] = srcV[j];
        }
        __syncthreads();

        // S = Q K^T   (16 x 64 per wave)
        f32x4 s[4];
        #pragma unroll
        for (int t = 0; t < 4; ++t) {
            f32x4 z = {0.f,0.f,0.f,0.f};
            s[t] = z;
            #pragma unroll
            for (int h = 0; h < 2; ++h) {
                bf16x8 bk = *(const bf16x8*)&Ks[(l & 15) + 16 * t][8 * (l >> 4) + 32 * h];
                s[t] = __builtin_amdgcn_mfma_f32_16x16x32_bf16(aq[h], bk, s[t], 0, 0, 0);
            }
        }

        // causal mask (only the diagonal tile is partial)
        if (it == nt - 1) {
            #pragma unroll
            for (int t = 0; t < 4; ++t)
                #pragma unroll
                for (int i = 0; i < 4; ++i) {
                    int key = k0 + (l & 15) + 16 * t;
                    int row = bq + w * 16 + (l >> 4) * 4 + i;
                    if (key > row) s[t][i] = -1e30f;
                }
        }

        // row max over 4 col-tiles and 16 lanes of the group
        f32x4 tmax = s[0];
        #pragma unroll
        for (int t = 1; t < 4; ++t)
            #pragma unroll
            for (int i = 0; i < 4; ++i) tmax[i] = fmaxf(tmax[i], s[t][i]);
        #pragma unroll
        for (int off = 1; off < 16; off <<= 1)
            #pragma unroll
            for (int i = 0; i < 4; ++i)
                tmax[i] = fmaxf(tmax[i], __shfl_xor(tmax[i], off, 64));

        f32x4 mnew, fac;
        #pragma unroll
        for (int i = 0; i < 4; ++i) {
            mnew[i] = fmaxf(mrow[i], tmax[i]);
            fac[i]  = expf(mrow[i] - mnew[i]);
        }

        // P = exp(S - mnew), write to LDS (bf16), row-sum
        f32x4 psum = {0.f, 0.f, 0.f, 0.f};
        #pragma unroll
        for (int t = 0; t < 4; ++t)
            #pragma unroll
            for (int i = 0; i < 4; ++i) {
                float p = expf(s[t][i] - mnew[i]);
                psum[i] += p;
                Ps[w][(l >> 4) * 4 + i][(l & 15) + 16 * t] = f2bf(p);
            }
        #pragma unroll
        for (int off = 1; off < 16; off <<= 1)
            #pragma unroll
            for (int i = 0; i < 4; ++i)
                psum[i] += __shfl_xor(psum[i], off, 64);

        #pragma unroll
        for (int i = 0; i < 4; ++i) {
            lsum[i] = lsum[i] * fac[i] + psum[i];
            mrow[i] = mnew[i];
        }
        #pragma unroll
        for (int t = 0; t < 4; ++t)
            #pragma unroll
            for (int i = 0; i < 4; ++i)
                accO[t][i] *= fac[i];

        // O += P V
        #pragma unroll
        for (int h = 0; h < 2; ++h) {
            bf16x8 pa = *(const bf16x8*)&Ps[w][l & 15][8 * (l >> 4) + 32 * h];
            #pragma unroll
            for (int t = 0; t < 4; ++t) {
                bf16x8 bv = *(const bf16x8*)&Vs[(l & 15) + 16 * t][8 * (l >> 4) + 32 * h];
                accO[t] = __builtin_amdgcn_mfma_f32_16x16x32_bf16(pa, bv, accO[t], 0, 0, 0);
            }
        }
    }

    // epilogue: out = O / lsum
    #pragma unroll
    for (int t = 0; t < 4; ++t)
        #pragma unroll
        for (int i = 0; i < 4; ++i) {
            int row = bq + w * 16 + (l >> 4) * 4 + i;
            int d = (l & 15) + 16 * t;
            out[(base + row) * 64 + d] = accO[t][i] / lsum[i];
        }
}

extern "C" void kernel_launch(void* const* d_in, const int* in_sizes, int n_in,
                              void* d_out, int out_size, void* d_ws, size_t ws_size,
                              hipStream_t stream) {
    // setup_inputs order: x, Wk, Wq, Wv
    const float* x  = (const float*)d_in[0];
    const float* Wk = (const float*)d_in[1];
    const float* Wq = (const float*)d_in[2];
    const float* Wv = (const float*)d_in[3];
    float* out = (float*)d_out;

    unsigned short* qw = (unsigned short*)d_ws;          // [16384][64] bf16
    unsigned short* kw = qw + (size_t)16384 * 64;
    unsigned short* vw = kw + (size_t)16384 * 64;

    hipLaunchKernelGGL(proj_kernel, dim3(256), dim3(256), 0, stream,
                       x, Wq, Wk, Wv, qw, kw, vw);
    hipLaunchKernelGGL(attn_kernel, dim3(64, 4), dim3(256), 0, stream,
                       qw, kw, vw, out);
}